// Round 7
// baseline (917.808 us; speedup 1.0000x reference)
//
#include <hip/hip_runtime.h>

#define Dd 2304
#define Hh 2304
#define G4 9216
#define TMAX 32
#define NSEQ 32
#define NBLK 192
#define SPIN_CAP 100000000u   // bail-out: converts a would-be hang into a wrong answer

typedef __bf16 bf16x8 __attribute__((ext_vector_type(8)));
typedef float f32x4 __attribute__((ext_vector_type(4)));
typedef unsigned short u16x8 __attribute__((ext_vector_type(8)));

// ---- workspace layout (bytes) ----
// meta page (16 KB = 4096 ints): [0..63] lens/maxlen/R, [64..2111] rsrc/rdst,
// [2560..2751] per-block epoch flags (stride 1), [3000] probe scratch
#define XP_OFF   16384ull                                   // xp fp32 [1024][9216]
#define WIHB_OFF (XP_OFF  + 1024ull * 9216ull * 4ull)       // W_ih bf16 [9216][2304]
#define ABF_OFF  (WIHB_OFF + 9216ull * 2304ull * 2ull)      // A bf16 [1024][2304]
#define HB_OFF   (ABF_OFF + 1024ull * 2304ull * 2ull)       // h bufs: 33 x [32][2304] bf16
#define FLAG_BASE 2560

static __device__ __forceinline__ unsigned short f2bf(float f) {
  unsigned int u = __float_as_uint(f);
  u += 0x7fffu + ((u >> 16) & 1u);        // RNE
  return (unsigned short)(u >> 16);
}
static __device__ __forceinline__ float bf2f(unsigned short u) {
  return __uint_as_float(((unsigned int)u) << 16);
}
static __device__ __forceinline__ float sigm(float x) { return 1.0f / (1.0f + expf(-x)); }

// h store write-through to LLC (sc0 sc1: bypass L1+L2 -> coherence point).
// Per-step h buffers: consumers' plain cached loads are first-touch -> pull
// current data from LLC, amortize across the XCD's L2. Zero cache maintenance
// in the step loop (validated R3).
static __device__ __forceinline__ void st_h_llc(unsigned short* p, unsigned short v) {
  asm volatile("global_store_short %0, %1, off sc0 sc1"
               :: "v"(p), "v"((unsigned)v) : "memory");
}

// async global->LDS 16B/lane (dest = wave-uniform base + lane*16, m97 pattern)
static __device__ __forceinline__ void gload_lds16(const unsigned short* g, unsigned short* l) {
  __builtin_amdgcn_global_load_lds(
      (const __attribute__((address_space(1))) unsigned int*)g,
      (__attribute__((address_space(3))) unsigned int*)l, 16, 0, 0);
}

// ---------------- prep: lengths, compacted row lists, barrier reset ----------------
__global__ void prep_kernel(const int* __restrict__ mask, const int* __restrict__ start,
                            const int* __restrict__ endp, int* __restrict__ meta) {
  __shared__ int len_s[16];
  const int tid = threadIdx.x;
  for (int i = 2112 + tid; i < 4096; i += 256)
    meta[i] = 0;                           // re-zero epoch flags + probe scratch
  if (tid < 16) {
    int s = 0;
    #pragma unroll 8
    for (int t = 0; t < 64; ++t) s += mask[tid * 64 + t];
    len_s[tid] = s;
  }
  __syncthreads();
  if (tid == 0) {
    int lens[NSEQ]; int ml = 0;
    for (int s = 0; s < NSEQ; ++s) {
      int l;
      if (s < 16) l = start[s] - 1;
      else        l = len_s[s - 16] - endp[s - 16];
      if (l < 1) l = 1;
      if (l > TMAX) l = TMAX;
      lens[s] = l; meta[s] = l; if (l > ml) ml = l;
    }
    meta[32] = ml;
    int* rsrc = meta + 64;
    int* rdst = meta + 64 + 1024;
    int R = 0;
    for (int s = 0; s < NSEQ; ++s) {
      const int b = s & 15;
      const int st = start[b], ln = len_s[b], en = endp[b];
      for (int t = 0; t < lens[s]; ++t) {
        int src = -1;
        if (s < 16) { if (t < st - 1)  src = (b * 64 + t + 1) * Dd; }
        else        { if (t < ln - en) src = (b * 64 + en + t) * Dd; }
        rsrc[R] = src; rdst[R] = s * TMAX + t; ++R;
      }
    }
    meta[33] = R;
    int i = R;  // pad remaining slots: epilogue writes land in never-read rows
    for (int s = 0; s < NSEQ; ++s)
      for (int t = lens[s]; t < TMAX; ++t) { rsrc[i] = -1; rdst[i] = s * TMAX + t; ++i; }
  }
}

// ---------------- cast W_ih fp32 -> bf16 (read once per element) ----------------
__global__ void cast_wih_kernel(const float4* __restrict__ in, uint2* __restrict__ out) {
  const int i = blockIdx.x * 256 + threadIdx.x;
  const float4 v = in[i];
  uint2 o;
  o.x = (unsigned)f2bf(v.x) | ((unsigned)f2bf(v.y) << 16);
  o.y = (unsigned)f2bf(v.z) | ((unsigned)f2bf(v.w) << 16);
  out[i] = o;
}

// ---------------- gather+cast A rows fp32 -> compact bf16 [1024][2304] ----------------
__global__ void cast_a_kernel(const float* __restrict__ feat, const int* __restrict__ meta,
                              uint4* __restrict__ abf) {
  const int r = blockIdx.x;
  const int src = meta[64 + r];
  const int tid = threadIdx.x;
  uint4* orow = abf + (size_t)r * 288;          // 2304 halves = 288 uint4
  for (int c = tid; c < 288; c += 256) {
    uint4 o = {0, 0, 0, 0};
    if (src >= 0) {
      const float4 f0 = *(const float4*)(feat + src + c * 8);
      const float4 f1 = *(const float4*)(feat + src + c * 8 + 4);
      o.x = (unsigned)f2bf(f0.x) | ((unsigned)f2bf(f0.y) << 16);
      o.y = (unsigned)f2bf(f0.z) | ((unsigned)f2bf(f0.w) << 16);
      o.z = (unsigned)f2bf(f1.x) | ((unsigned)f2bf(f1.y) << 16);
      o.w = (unsigned)f2bf(f1.z) | ((unsigned)f2bf(f1.w) << 16);
    }
    orow[c] = o;
  }
}

// ---------------- xp GEMM: m97 structure (global_load_lds w=16, linear LDS) ----------------
__global__ __launch_bounds__(256) void xp_gemm(
    const unsigned short* __restrict__ abf, const unsigned short* __restrict__ wihb,
    const float* __restrict__ bih, const float* __restrict__ bhh,
    const int* __restrict__ meta, float* __restrict__ xp)
{
  const int R = meta[33];
  const int m0 = blockIdx.y * 128;
  if (m0 >= R) return;
  const int n0 = blockIdx.x * 128;
  __shared__ unsigned short As[128 * 32];
  __shared__ unsigned short Bs[128 * 32];
  const int tid = threadIdx.x;
  const int w = tid >> 6, lane = tid & 63;
  const int l16 = lane & 15, quad = lane >> 4;
  const int wm = (w >> 1) * 64, wn = (w & 1) * 64;
  const int* rdst = meta + 64 + 1024;

  const int rg = lane >> 2;                   // row within 16-row region
  const int kc = (lane & 3) * 8;              // k-chunk (elems)
  const unsigned short* gA0 = abf  + (size_t)(m0 + (w * 2 + 0) * 16 + rg) * Dd + kc;
  const unsigned short* gA1 = abf  + (size_t)(m0 + (w * 2 + 1) * 16 + rg) * Dd + kc;
  const unsigned short* gB0 = wihb + (size_t)(n0 + (w * 2 + 0) * 16 + rg) * Dd + kc;
  const unsigned short* gB1 = wihb + (size_t)(n0 + (w * 2 + 1) * 16 + rg) * Dd + kc;
  unsigned short* lA0 = &As[(w * 2 + 0) * 512];
  unsigned short* lA1 = &As[(w * 2 + 1) * 512];
  unsigned short* lB0 = &Bs[(w * 2 + 0) * 512];
  unsigned short* lB1 = &Bs[(w * 2 + 1) * 512];

  f32x4 acc[4][4] = {};
  for (int kk = 0; kk < Dd; kk += 32) {
    __syncthreads();                          // prev iter's frag reads done
    gload_lds16(gA0 + kk, lA0);
    gload_lds16(gA1 + kk, lA1);
    gload_lds16(gB0 + kk, lB0);
    gload_lds16(gB1 + kk, lB1);
    __syncthreads();                          // DMA landed (each wave drains vmcnt)
    bf16x8 af[4], bfr[4];
    #pragma unroll
    for (int i = 0; i < 4; ++i) {
      af[i]  = __builtin_bit_cast(bf16x8, *(const u16x8*)&As[(wm + i * 16 + l16) * 32 + quad * 8]);
      bfr[i] = __builtin_bit_cast(bf16x8, *(const u16x8*)&Bs[(wn + i * 16 + l16) * 32 + quad * 8]);
    }
    #pragma unroll
    for (int mi = 0; mi < 4; ++mi)
      #pragma unroll
      for (int ni = 0; ni < 4; ++ni)
        acc[mi][ni] = __builtin_amdgcn_mfma_f32_16x16x32_bf16(af[mi], bfr[ni], acc[mi][ni], 0, 0, 0);
  }
  #pragma unroll
  for (int ni = 0; ni < 4; ++ni) {
    const int col = n0 + wn + ni * 16 + l16;
    const float bsum = bih[col] + bhh[col];
    #pragma unroll
    for (int mi = 0; mi < 4; ++mi)
      #pragma unroll
      for (int r = 0; r < 4; ++r) {
        const int row = m0 + wm + mi * 16 + quad * 4 + r;
        const int dr = rdst[row];
        xp[(size_t)dr * G4 + col] = acc[mi][ni][r] + bsum;
      }
  }
}

// ---------------- persistent LSTM: 192 blocks x 256 thr (R3 structure, unchanged) ----------------
__global__ __launch_bounds__(256, 1) void lstm_persist(
    const float* __restrict__ whh, const float* __restrict__ xp,
    int* __restrict__ meta, unsigned short* __restrict__ hb,
    const float* __restrict__ wout, const float* __restrict__ bout,
    float* __restrict__ out)
{
  const int tid = threadIdx.x;
  const int bid = blockIdx.x;
  const int j0 = bid * 12;
  const int w = tid >> 6, lane = tid & 63;
  const int l16 = lane & 15, quad = lane >> 4;
  const int maxlen = meta[32];
  int* flags = meta + FLAG_BASE;
#define HBUF(t) (hb + (size_t)(t) * (NSEQ * Hh))

  __shared__ float red[4][32][49];

  // ---- W_hh slice -> registers (fp32 read once, cvt bf16) ----
  u16x8 Bfr[54];
  #pragma unroll
  for (int n = 0; n < 3; ++n) {
    const int rl = n * 16 + l16;              // local gate-row 0..47
    const int g = rl / 12, j = rl - g * 12;   // (gate, hidden-unit-in-block)
    const float* bp = whh + (size_t)(g * Hh + j0 + j) * Hh + w * 576 + quad * 8;
    #pragma unroll
    for (int kf = 0; kf < 18; ++kf) {
      const float4 f0 = *(const float4*)(bp + kf * 32);
      const float4 f1 = *(const float4*)(bp + kf * 32 + 4);
      u16x8 v;
      v[0] = f2bf(f0.x); v[1] = f2bf(f0.y); v[2] = f2bf(f0.z); v[3] = f2bf(f0.w);
      v[4] = f2bf(f1.x); v[5] = f2bf(f1.y); v[6] = f2bf(f1.z); v[7] = f2bf(f1.w);
      Bfr[n * 18 + kf] = v;
    }
  }

  // pointwise cells: cell0 = tid, cell1 = 256+tid (tid<128); 384 = 32 seqs x 12 j
  const int sA = tid / 12, jA = tid - sA * 12;
  const int cB = 256 + tid;
  const int sB = cB / 12, jB = cB - sB * 12;
  const int lenA = meta[sA];
  const int lenB = (tid < 128) ? meta[sB] : 0;
  float cstA = 0.f, hvA = 0.f, cstB = 0.f, hvB = 0.f;

  // ---- step 0: h(0)=0 so gates = xp(s,0); write h(1) ----
  {
    const float* p = xp + (size_t)(sA * TMAX) * G4 + j0 + jA;
    const float vi = p[0], vg = p[2 * Hh], vo = p[3 * Hh];
    cstA = sigm(vi) * tanhf(vg);
    hvA = sigm(vo) * tanhf(cstA);
    st_h_llc(HBUF(1) + sA * Hh + j0 + jA, f2bf(hvA));
    if (tid < 128) {
      const float* q = xp + (size_t)(sB * TMAX) * G4 + j0 + jB;
      const float wi = q[0], wg = q[2 * Hh], wo = q[3 * Hh];
      cstB = sigm(wi) * tanhf(wg);
      hvB = sigm(wo) * tanhf(cstB);
      st_h_llc(HBUF(1) + sB * Hh + j0 + jB, f2bf(hvB));
    }
  }

  // ---- flat barrier, epoch 1 (+ xp[1] prefetch under barrier skew) ----
  float xiA, xfA, xgA, xoA, xiB = 0, xfB = 0, xgB = 0, xoB = 0;
  asm volatile("s_waitcnt vmcnt(0)" ::: "memory");   // asm h-stores acked at LLC
  __syncthreads();
  if (tid == 0)
    __hip_atomic_store(flags + bid, 1, __ATOMIC_RELAXED, __HIP_MEMORY_SCOPE_AGENT);
  if (1 < maxlen) {
    { const float* p = xp + (size_t)(sA * TMAX + 1) * G4 + j0 + jA;
      xiA = p[0]; xfA = p[Hh]; xgA = p[2 * Hh]; xoA = p[3 * Hh]; }
    if (tid < 128) {
      const float* q = xp + (size_t)(sB * TMAX + 1) * G4 + j0 + jB;
      xiB = q[0]; xfB = q[Hh]; xgB = q[2 * Hh]; xoB = q[3 * Hh];
    }
  }
  if (tid < NBLK) {
    unsigned spin = 0;
    while (__hip_atomic_load(flags + tid, __ATOMIC_RELAXED, __HIP_MEMORY_SCOPE_AGENT) < 1 &&
           ++spin < SPIN_CAP)
      __builtin_amdgcn_s_sleep(2);
  }
  __syncthreads();

  // ---- steps 1..maxlen-1 ----
  for (int t = 1; t < maxlen; ++t) {
    const unsigned short* hin = HBUF(t);        // fresh addresses: first touch this step
    unsigned short* hout      = HBUF(t + 1);
    f32x4 acc[2][3] = {};
    const unsigned short* pa = hin + (size_t)l16 * Hh + w * 576 + quad * 8;
    #pragma unroll
    for (int kf = 0; kf < 18; ++kf) {
      const bf16x8 a0 = __builtin_bit_cast(bf16x8, *(const u16x8*)(pa + kf * 32));
      const bf16x8 a1 = __builtin_bit_cast(bf16x8, *(const u16x8*)(pa + kf * 32 + 16 * Hh));
      #pragma unroll
      for (int n = 0; n < 3; ++n) {
        const bf16x8 bv = __builtin_bit_cast(bf16x8, Bfr[n * 18 + kf]);
        acc[0][n] = __builtin_amdgcn_mfma_f32_16x16x32_bf16(a0, bv, acc[0][n], 0, 0, 0);
        acc[1][n] = __builtin_amdgcn_mfma_f32_16x16x32_bf16(a1, bv, acc[1][n], 0, 0, 0);
      }
    }
    #pragma unroll
    for (int m = 0; m < 2; ++m)
      #pragma unroll
      for (int n = 0; n < 3; ++n)
        #pragma unroll
        for (int r = 0; r < 4; ++r)
          red[w][m * 16 + quad * 4 + r][n * 16 + l16] = acc[m][n][r];
    __syncthreads();
    if (t < lenA) {
      const float vi = xiA + red[0][sA][jA]      + red[1][sA][jA]      + red[2][sA][jA]      + red[3][sA][jA];
      const float vf = xfA + red[0][sA][12 + jA] + red[1][sA][12 + jA] + red[2][sA][12 + jA] + red[3][sA][12 + jA];
      const float vg = xgA + red[0][sA][24 + jA] + red[1][sA][24 + jA] + red[2][sA][24 + jA] + red[3][sA][24 + jA];
      const float vo = xoA + red[0][sA][36 + jA] + red[1][sA][36 + jA] + red[2][sA][36 + jA] + red[3][sA][36 + jA];
      cstA = sigm(vf) * cstA + sigm(vi) * tanhf(vg);
      hvA = sigm(vo) * tanhf(cstA);
    }
    st_h_llc(hout + sA * Hh + j0 + jA, f2bf(hvA));
    if (tid < 128) {
      if (t < lenB) {
        const float vi = xiB + red[0][sB][jB]      + red[1][sB][jB]      + red[2][sB][jB]      + red[3][sB][jB];
        const float vf = xfB + red[0][sB][12 + jB] + red[1][sB][12 + jB] + red[2][sB][12 + jB] + red[3][sB][12 + jB];
        const float vg = xgB + red[0][sB][24 + jB] + red[1][sB][24 + jB] + red[2][sB][24 + jB] + red[3][sB][24 + jB];
        const float vo = xoB + red[0][sB][36 + jB] + red[1][sB][36 + jB] + red[2][sB][36 + jB] + red[3][sB][36 + jB];
        cstB = sigm(vf) * cstB + sigm(vi) * tanhf(vg);
        hvB = sigm(vo) * tanhf(cstB);
      }
      st_h_llc(hout + sB * Hh + j0 + jB, f2bf(hvB));
    }
    // ---- flat barrier, epoch t+1 (+ xp[t+1] prefetch under barrier skew) ----
    asm volatile("s_waitcnt vmcnt(0)" ::: "memory");
    __syncthreads();
    if (tid == 0)
      __hip_atomic_store(flags + bid, t + 1, __ATOMIC_RELAXED, __HIP_MEMORY_SCOPE_AGENT);
    if (t + 1 < maxlen) {
      { const float* p = xp + (size_t)(sA * TMAX + t + 1) * G4 + j0 + jA;
        xiA = p[0]; xfA = p[Hh]; xgA = p[2 * Hh]; xoA = p[3 * Hh]; }
      if (tid < 128) {
        const float* q = xp + (size_t)(sB * TMAX + t + 1) * G4 + j0 + jB;
        xiB = q[0]; xfB = q[Hh]; xgB = q[2 * Hh]; xoB = q[3 * Hh];
      }
    }
    if (tid < NBLK) {
      unsigned spin = 0;
      while (__hip_atomic_load(flags + tid, __ATOMIC_RELAXED, __HIP_MEMORY_SCOPE_AGENT) < t + 1 &&
             ++spin < SPIN_CAP)
        __builtin_amdgcn_s_sleep(2);
    }
    __syncthreads();
  }

  // ---- fused output projection: block covers e-cols bid*4..+3 ----
  const unsigned short* hf = HBUF(maxlen);
  const int o = tid >> 2, p4 = tid & 3;     // 64 outputs/block, 4 K-parts each
  const int ee = o & 3, bb = o >> 2;
  const int e = bid * 4 + ee;
  const int hrow = (p4 < 2) ? bb : (16 + bb);
  const int kb = (p4 & 1) * 1152;
  const unsigned short* hp = hf + hrow * Hh + kb;
  const float* wp = wout + (size_t)e * 4608 + p4 * 1152;
  float acco = 0.f;
  #pragma unroll 4
  for (int i = 0; i < 1152; i += 8) {
    const u16x8 hv = *(const u16x8*)(hp + i);
    const float4 w0 = *(const float4*)(wp + i);
    const float4 w1 = *(const float4*)(wp + i + 4);
    acco += bf2f(hv[0]) * w0.x + bf2f(hv[1]) * w0.y + bf2f(hv[2]) * w0.z + bf2f(hv[3]) * w0.w
          + bf2f(hv[4]) * w1.x + bf2f(hv[5]) * w1.y + bf2f(hv[6]) * w1.z + bf2f(hv[7]) * w1.w;
  }
  acco += __shfl_xor(acco, 1);
  acco += __shfl_xor(acco, 2);
  if (p4 == 0) out[bb * 768 + e] = acco + bout[e];
}

// ---------------- SCLK probe: spin a fixed 2^19 shader-clock ticks ----------------
// Own dispatch row in the profile: dur_us = 524288 / SCLK.
//   2.4 GHz -> ~218 us | 1.2 GHz -> ~437 | 0.6 GHz -> ~874 | const-100MHz ctr -> ~5240
__global__ void clock_probe(int* __restrict__ meta) {
  if (threadIdx.x == 0) {
    const long long t0 = clock64();
    long long t = t0;
    unsigned it = 0;
    while ((t - t0) < (1ll << 19) && ++it < 2000000u) t = clock64();
    meta[3000] = (int)(t - t0);             // side effect: keep the loop
  }
}

extern "C" void kernel_launch(void* const* d_in, const int* in_sizes, int n_in,
                              void* d_out, int out_size, void* d_ws, size_t ws_size,
                              hipStream_t stream)
{
  const float* feat = (const float*)d_in[0];
  const int* mask   = (const int*)d_in[1];
  const int* start  = (const int*)d_in[2];
  const int* endp   = (const int*)d_in[3];
  const float* wih  = (const float*)d_in[4];
  const float* whh  = (const float*)d_in[5];
  const float* bih  = (const float*)d_in[6];
  const float* bhh  = (const float*)d_in[7];
  const float* wout = (const float*)d_in[8];
  const float* bout = (const float*)d_in[9];
  float* out = (float*)d_out;
  char* ws = (char*)d_ws;

  int* meta = (int*)ws;
  float* xp = (float*)(ws + XP_OFF);
  unsigned short* wihb = (unsigned short*)(ws + WIHB_OFF);
  unsigned short* abf  = (unsigned short*)(ws + ABF_OFF);
  unsigned short* hb   = (unsigned short*)(ws + HB_OFF);

  hipLaunchKernelGGL(prep_kernel, dim3(1), dim3(256), 0, stream, mask, start, endp, meta);
  hipLaunchKernelGGL(cast_wih_kernel, dim3(20736), dim3(256), 0, stream,
                     (const float4*)wih, (uint2*)wihb);
  hipLaunchKernelGGL(cast_a_kernel, dim3(1024), dim3(256), 0, stream,
                     feat, meta, (uint4*)abf);
  hipLaunchKernelGGL(xp_gemm, dim3(72, 8), dim3(256), 0, stream,
                     abf, wihb, bih, bhh, meta, xp);
  hipLaunchKernelGGL(lstm_persist, dim3(NBLK), dim3(256), 0, stream,
                     whh, xp, meta, hb, wout, bout, out);
  hipLaunchKernelGGL(clock_probe, dim3(1), dim3(64), 0, stream, meta);
}

// Round 8
// 630.926 us; speedup vs baseline: 1.4547x; 1.4547x over previous
//
#include <hip/hip_runtime.h>

#define Dd 2304
#define Hh 2304
#define G4 9216
#define TMAX 32
#define NSEQ 32
#define NBLK 192
#define SPIN_CAP 100000000u   // bail-out: converts a would-be hang into a wrong answer

typedef __bf16 bf16x8 __attribute__((ext_vector_type(8)));
typedef float f32x4 __attribute__((ext_vector_type(4)));
typedef unsigned short u16x8 __attribute__((ext_vector_type(8)));

// ---- workspace layout (bytes) ----
// meta page (16 KB = 4096 ints): [0..63] lens/maxlen/R, [64..2111] rsrc/rdst,
// [2560..2751] per-block epoch flags (stride 1)
#define XP_OFF   16384ull                                   // xp fp32 [1024][9216]
#define WIHB_OFF (XP_OFF  + 1024ull * 9216ull * 4ull)       // W_ih bf16 [9216][2304]
#define ABF_OFF  (WIHB_OFF + 9216ull * 2304ull * 2ull)      // A bf16 [1024][2304]
#define HB_OFF   (ABF_OFF + 1024ull * 2304ull * 2ull)       // h bufs: 33 x [32][2304] bf16
#define FLAG_BASE 2560

static __device__ __forceinline__ unsigned short f2bf(float f) {
  unsigned int u = __float_as_uint(f);
  u += 0x7fffu + ((u >> 16) & 1u);        // RNE
  return (unsigned short)(u >> 16);
}
static __device__ __forceinline__ float bf2f(unsigned short u) {
  return __uint_as_float(((unsigned int)u) << 16);
}
static __device__ __forceinline__ float sigm(float x) { return 1.0f / (1.0f + expf(-x)); }

// h store write-through to LLC (sc0 sc1: bypass L1+L2 -> coherence point).
// Per-step h buffers: consumers' first-touch reads pull current data via L2 from
// LLC with intra-XCD amortization. Zero cache maintenance in the step loop.
static __device__ __forceinline__ void st_h_llc(unsigned short* p, unsigned short v) {
  asm volatile("global_store_short %0, %1, off sc0 sc1"
               :: "v"(p), "v"((unsigned)v) : "memory");
}

// async global->LDS 16B/lane (dest = wave-uniform base + lane*16; src per-lane)
static __device__ __forceinline__ void gload_lds16(const unsigned short* g, unsigned short* l) {
  __builtin_amdgcn_global_load_lds(
      (const __attribute__((address_space(1))) unsigned int*)g,
      (__attribute__((address_space(3))) unsigned int*)l, 16, 0, 0);
}

// ---------------- prep: lengths, compacted row lists, barrier reset ----------------
__global__ void prep_kernel(const int* __restrict__ mask, const int* __restrict__ start,
                            const int* __restrict__ endp, int* __restrict__ meta) {
  __shared__ int len_s[16];
  const int tid = threadIdx.x;
  for (int i = 2112 + tid; i < 4096; i += 256)
    meta[i] = 0;                           // re-zero epoch flags
  if (tid < 16) {
    int s = 0;
    #pragma unroll 8
    for (int t = 0; t < 64; ++t) s += mask[tid * 64 + t];
    len_s[tid] = s;
  }
  __syncthreads();
  if (tid == 0) {
    int lens[NSEQ]; int ml = 0;
    for (int s = 0; s < NSEQ; ++s) {
      int l;
      if (s < 16) l = start[s] - 1;
      else        l = len_s[s - 16] - endp[s - 16];
      if (l < 1) l = 1;
      if (l > TMAX) l = TMAX;
      lens[s] = l; meta[s] = l; if (l > ml) ml = l;
    }
    meta[32] = ml;
    int* rsrc = meta + 64;
    int* rdst = meta + 64 + 1024;
    int R = 0;
    for (int s = 0; s < NSEQ; ++s) {
      const int b = s & 15;
      const int st = start[b], ln = len_s[b], en = endp[b];
      for (int t = 0; t < lens[s]; ++t) {
        int src = -1;
        if (s < 16) { if (t < st - 1)  src = (b * 64 + t + 1) * Dd; }
        else        { if (t < ln - en) src = (b * 64 + en + t) * Dd; }
        rsrc[R] = src; rdst[R] = s * TMAX + t; ++R;
      }
    }
    meta[33] = R;
    int i = R;  // pad remaining slots: epilogue writes land in never-read rows
    for (int s = 0; s < NSEQ; ++s)
      for (int t = lens[s]; t < TMAX; ++t) { rsrc[i] = -1; rdst[i] = s * TMAX + t; ++i; }
  }
}

// ---------------- cast W_ih fp32 -> bf16 (read once per element) ----------------
__global__ void cast_wih_kernel(const float4* __restrict__ in, uint2* __restrict__ out) {
  const int i = blockIdx.x * 256 + threadIdx.x;
  const float4 v = in[i];
  uint2 o;
  o.x = (unsigned)f2bf(v.x) | ((unsigned)f2bf(v.y) << 16);
  o.y = (unsigned)f2bf(v.z) | ((unsigned)f2bf(v.w) << 16);
  out[i] = o;
}

// ---------------- gather+cast A rows fp32 -> compact bf16 [1024][2304] ----------------
__global__ void cast_a_kernel(const float* __restrict__ feat, const int* __restrict__ meta,
                              uint4* __restrict__ abf) {
  const int r = blockIdx.x;
  const int src = meta[64 + r];
  const int tid = threadIdx.x;
  uint4* orow = abf + (size_t)r * 288;          // 2304 halves = 288 uint4
  for (int c = tid; c < 288; c += 256) {
    uint4 o = {0, 0, 0, 0};
    if (src >= 0) {
      const float4 f0 = *(const float4*)(feat + src + c * 8);
      const float4 f1 = *(const float4*)(feat + src + c * 8 + 4);
      o.x = (unsigned)f2bf(f0.x) | ((unsigned)f2bf(f0.y) << 16);
      o.y = (unsigned)f2bf(f0.z) | ((unsigned)f2bf(f0.w) << 16);
      o.z = (unsigned)f2bf(f1.x) | ((unsigned)f2bf(f1.y) << 16);
      o.w = (unsigned)f2bf(f1.z) | ((unsigned)f2bf(f1.w) << 16);
    }
    orow[c] = o;
  }
}

// ---------------- xp GEMM: m97 structure (global_load_lds w=16, linear LDS) ----------------
__global__ __launch_bounds__(256) void xp_gemm(
    const unsigned short* __restrict__ abf, const unsigned short* __restrict__ wihb,
    const float* __restrict__ bih, const float* __restrict__ bhh,
    const int* __restrict__ meta, float* __restrict__ xp)
{
  const int R = meta[33];
  const int m0 = blockIdx.y * 128;
  if (m0 >= R) return;
  const int n0 = blockIdx.x * 128;
  __shared__ unsigned short As[128 * 32];
  __shared__ unsigned short Bs[128 * 32];
  const int tid = threadIdx.x;
  const int w = tid >> 6, lane = tid & 63;
  const int l16 = lane & 15, quad = lane >> 4;
  const int wm = (w >> 1) * 64, wn = (w & 1) * 64;
  const int* rdst = meta + 64 + 1024;

  const int rg = lane >> 2;                   // row within 16-row region
  const int kc = (lane & 3) * 8;              // k-chunk (elems)
  const unsigned short* gA0 = abf  + (size_t)(m0 + (w * 2 + 0) * 16 + rg) * Dd + kc;
  const unsigned short* gA1 = abf  + (size_t)(m0 + (w * 2 + 1) * 16 + rg) * Dd + kc;
  const unsigned short* gB0 = wihb + (size_t)(n0 + (w * 2 + 0) * 16 + rg) * Dd + kc;
  const unsigned short* gB1 = wihb + (size_t)(n0 + (w * 2 + 1) * 16 + rg) * Dd + kc;
  unsigned short* lA0 = &As[(w * 2 + 0) * 512];
  unsigned short* lA1 = &As[(w * 2 + 1) * 512];
  unsigned short* lB0 = &Bs[(w * 2 + 0) * 512];
  unsigned short* lB1 = &Bs[(w * 2 + 1) * 512];

  f32x4 acc[4][4] = {};
  for (int kk = 0; kk < Dd; kk += 32) {
    __syncthreads();                          // prev iter's frag reads done
    gload_lds16(gA0 + kk, lA0);
    gload_lds16(gA1 + kk, lA1);
    gload_lds16(gB0 + kk, lB0);
    gload_lds16(gB1 + kk, lB1);
    __syncthreads();                          // DMA landed (each wave drains vmcnt)
    bf16x8 af[4], bfr[4];
    #pragma unroll
    for (int i = 0; i < 4; ++i) {
      af[i]  = __builtin_bit_cast(bf16x8, *(const u16x8*)&As[(wm + i * 16 + l16) * 32 + quad * 8]);
      bfr[i] = __builtin_bit_cast(bf16x8, *(const u16x8*)&Bs[(wn + i * 16 + l16) * 32 + quad * 8]);
    }
    #pragma unroll
    for (int mi = 0; mi < 4; ++mi)
      #pragma unroll
      for (int ni = 0; ni < 4; ++ni)
        acc[mi][ni] = __builtin_amdgcn_mfma_f32_16x16x32_bf16(af[mi], bfr[ni], acc[mi][ni], 0, 0, 0);
  }
  #pragma unroll
  for (int ni = 0; ni < 4; ++ni) {
    const int col = n0 + wn + ni * 16 + l16;
    const float bsum = bih[col] + bhh[col];
    #pragma unroll
    for (int mi = 0; mi < 4; ++mi)
      #pragma unroll
      for (int r = 0; r < 4; ++r) {
        const int row = m0 + wm + mi * 16 + quad * 4 + r;
        const int dr = rdst[row];
        xp[(size_t)dr * G4 + col] = acc[mi][ni][r] + bsum;
      }
  }
}

// ---------------- persistent LSTM: 192 blocks x 256 thr ----------------
// Block owns 12 hidden units x 4 gates (48 W_hh rows) in 216 VGPRs/thread -> only
// ~0 spare VGPRs, so register h-loads serialize into 18 LLC RTTs/step (the R0-R6
// ~14us/step floor; clock-droop falsified by R7 probe at ~2.5 GHz). FIX: stage h
// via global_load_lds (zero VGPR cost, all loads in flight), per-wave chunks of
// 6 kf double-buffered, counted vmcnt pipeline, MFMA A-frags from LDS.
__global__ __launch_bounds__(256, 1) void lstm_persist(
    const float* __restrict__ whh, const float* __restrict__ xp,
    int* __restrict__ meta, unsigned short* __restrict__ hb,
    const float* __restrict__ wout, const float* __restrict__ bout,
    float* __restrict__ out)
{
  const int tid = threadIdx.x;
  const int bid = blockIdx.x;
  const int j0 = bid * 12;
  const int w = tid >> 6, lane = tid & 63;
  const int l16 = lane & 15, quad = lane >> 4;
  const int maxlen = meta[32];
  int* flags = meta + FLAG_BASE;
#define HBUF(t) (hb + (size_t)(t) * (NSEQ * Hh))

  __shared__ float red[4][32][49];                 // 25,088 B
  __shared__ unsigned short hstage[4 * 12288];     // 98,304 B: 4 waves x 2 bufs x 6 tiles(2KB)

  // ---- W_hh slice -> registers (fp32 read once, cvt bf16) ----
  u16x8 Bfr[54];
  #pragma unroll
  for (int n = 0; n < 3; ++n) {
    const int rl = n * 16 + l16;              // local gate-row 0..47
    const int g = rl / 12, j = rl - g * 12;   // (gate, hidden-unit-in-block)
    const float* bp = whh + (size_t)(g * Hh + j0 + j) * Hh + w * 576 + quad * 8;
    #pragma unroll
    for (int kf = 0; kf < 18; ++kf) {
      const float4 f0 = *(const float4*)(bp + kf * 32);
      const float4 f1 = *(const float4*)(bp + kf * 32 + 4);
      u16x8 v;
      v[0] = f2bf(f0.x); v[1] = f2bf(f0.y); v[2] = f2bf(f0.z); v[3] = f2bf(f0.w);
      v[4] = f2bf(f1.x); v[5] = f2bf(f1.y); v[6] = f2bf(f1.z); v[7] = f2bf(f1.w);
      Bfr[n * 18 + kf] = v;
    }
  }

  // per-lane global offset for h staging: seq = lane/4, colgroup = lane%4 (16B)
  const int hlane = (lane >> 2) * Hh + w * 576 + (lane & 3) * 8;

// chunk c (6 kf = 192 cols) of wave w's K-slice -> LDS buf b. Dest is wave-uniform
// (+16B/lane implied); tile layout: [seq 0..15][32 cols] then [seq 16..31][32 cols].
#define ISSUE_CHUNK(c, b) { \
    const unsigned short* gk = hin + hlane + (c) * 192; \
    unsigned short* lk = hstage + w * 12288 + (b) * 6144; \
    _Pragma("unroll") \
    for (int t6 = 0; t6 < 6; ++t6) { \
      gload_lds16(gk + t6 * 32,           lk + t6 * 1024); \
      gload_lds16(gk + t6 * 32 + 16 * Hh, lk + t6 * 1024 + 512); \
    } }

#define COMPUTE_CHUNK(c, b) { \
    const unsigned short* lbw = hstage + w * 12288 + (b) * 6144 + l16 * 32 + quad * 8; \
    _Pragma("unroll") \
    for (int t6 = 0; t6 < 6; ++t6) { \
      const bf16x8 a0 = __builtin_bit_cast(bf16x8, *(const u16x8*)(lbw + t6 * 1024)); \
      const bf16x8 a1 = __builtin_bit_cast(bf16x8, *(const u16x8*)(lbw + t6 * 1024 + 512)); \
      _Pragma("unroll") \
      for (int n = 0; n < 3; ++n) { \
        const bf16x8 bv = __builtin_bit_cast(bf16x8, Bfr[n * 18 + (c) * 6 + t6]); \
        acc[0][n] = __builtin_amdgcn_mfma_f32_16x16x32_bf16(a0, bv, acc[0][n], 0, 0, 0); \
        acc[1][n] = __builtin_amdgcn_mfma_f32_16x16x32_bf16(a1, bv, acc[1][n], 0, 0, 0); \
      } \
    } }

  // pointwise cells: cell0 = tid, cell1 = 256+tid (tid<128); 384 = 32 seqs x 12 j
  const int sA = tid / 12, jA = tid - sA * 12;
  const int cB = 256 + tid;
  const int sB = cB / 12, jB = cB - sB * 12;
  const int lenA = meta[sA];
  const int lenB = (tid < 128) ? meta[sB] : 0;
  float cstA = 0.f, hvA = 0.f, cstB = 0.f, hvB = 0.f;

  // ---- step 0: h(0)=0 so gates = xp(s,0); write h(1) ----
  {
    const float* p = xp + (size_t)(sA * TMAX) * G4 + j0 + jA;
    const float vi = p[0], vg = p[2 * Hh], vo = p[3 * Hh];
    cstA = sigm(vi) * tanhf(vg);
    hvA = sigm(vo) * tanhf(cstA);
    st_h_llc(HBUF(1) + sA * Hh + j0 + jA, f2bf(hvA));
    if (tid < 128) {
      const float* q = xp + (size_t)(sB * TMAX) * G4 + j0 + jB;
      const float wi = q[0], wg = q[2 * Hh], wo = q[3 * Hh];
      cstB = sigm(wi) * tanhf(wg);
      hvB = sigm(wo) * tanhf(cstB);
      st_h_llc(HBUF(1) + sB * Hh + j0 + jB, f2bf(hvB));
    }
  }

  // ---- flat barrier, epoch 1 (+ xp[1] prefetch under barrier skew) ----
  float xiA, xfA, xgA, xoA, xiB = 0, xfB = 0, xgB = 0, xoB = 0;
  asm volatile("s_waitcnt vmcnt(0)" ::: "memory");   // asm h-stores acked at LLC
  __syncthreads();
  if (tid == 0)
    __hip_atomic_store(flags + bid, 1, __ATOMIC_RELAXED, __HIP_MEMORY_SCOPE_AGENT);
  if (1 < maxlen) {
    { const float* p = xp + (size_t)(sA * TMAX + 1) * G4 + j0 + jA;
      xiA = p[0]; xfA = p[Hh]; xgA = p[2 * Hh]; xoA = p[3 * Hh]; }
    if (tid < 128) {
      const float* q = xp + (size_t)(sB * TMAX + 1) * G4 + j0 + jB;
      xiB = q[0]; xfB = q[Hh]; xgB = q[2 * Hh]; xoB = q[3 * Hh];
    }
  }
  if (tid < NBLK) {
    unsigned spin = 0;
    while (__hip_atomic_load(flags + tid, __ATOMIC_RELAXED, __HIP_MEMORY_SCOPE_AGENT) < 1 &&
           ++spin < SPIN_CAP)
      __builtin_amdgcn_s_sleep(2);
  }
  __syncthreads();

  // ---- steps 1..maxlen-1 ----
  for (int t = 1; t < maxlen; ++t) {
    const unsigned short* hin = HBUF(t);        // fresh addresses: first touch this step
    unsigned short* hout      = HBUF(t + 1);
    f32x4 acc[2][3] = {};
    // pipelined staged gates-GEMM: all of a chunk's 12 DMA loads in flight at once
    ISSUE_CHUNK(0, 0);
    ISSUE_CHUNK(1, 1);
    asm volatile("s_waitcnt vmcnt(12)" ::: "memory");   // chunk0 landed (oldest 12)
    __builtin_amdgcn_sched_barrier(0);
    COMPUTE_CHUNK(0, 0);
    asm volatile("s_waitcnt lgkmcnt(0)" ::: "memory");  // chunk0 ds_reads retired
    __builtin_amdgcn_sched_barrier(0);
    ISSUE_CHUNK(2, 0);                                  // reuse buf0
    asm volatile("s_waitcnt vmcnt(12)" ::: "memory");   // chunk1 landed
    __builtin_amdgcn_sched_barrier(0);
    COMPUTE_CHUNK(1, 1);
    asm volatile("s_waitcnt vmcnt(0)" ::: "memory");    // chunk2 landed
    __builtin_amdgcn_sched_barrier(0);
    COMPUTE_CHUNK(2, 0);
    #pragma unroll
    for (int m = 0; m < 2; ++m)
      #pragma unroll
      for (int n = 0; n < 3; ++n)
        #pragma unroll
        for (int r = 0; r < 4; ++r)
          red[w][m * 16 + quad * 4 + r][n * 16 + l16] = acc[m][n][r];
    __syncthreads();
    if (t < lenA) {
      const float vi = xiA + red[0][sA][jA]      + red[1][sA][jA]      + red[2][sA][jA]      + red[3][sA][jA];
      const float vf = xfA + red[0][sA][12 + jA] + red[1][sA][12 + jA] + red[2][sA][12 + jA] + red[3][sA][12 + jA];
      const float vg = xgA + red[0][sA][24 + jA] + red[1][sA][24 + jA] + red[2][sA][24 + jA] + red[3][sA][24 + jA];
      const float vo = xoA + red[0][sA][36 + jA] + red[1][sA][36 + jA] + red[2][sA][36 + jA] + red[3][sA][36 + jA];
      cstA = sigm(vf) * cstA + sigm(vi) * tanhf(vg);
      hvA = sigm(vo) * tanhf(cstA);
    }
    st_h_llc(hout + sA * Hh + j0 + jA, f2bf(hvA));
    if (tid < 128) {
      if (t < lenB) {
        const float vi = xiB + red[0][sB][jB]      + red[1][sB][jB]      + red[2][sB][jB]      + red[3][sB][jB];
        const float vf = xfB + red[0][sB][12 + jB] + red[1][sB][12 + jB] + red[2][sB][12 + jB] + red[3][sB][12 + jB];
        const float vg = xgB + red[0][sB][24 + jB] + red[1][sB][24 + jB] + red[2][sB][24 + jB] + red[3][sB][24 + jB];
        const float vo = xoB + red[0][sB][36 + jB] + red[1][sB][36 + jB] + red[2][sB][36 + jB] + red[3][sB][36 + jB];
        cstB = sigm(vf) * cstB + sigm(vi) * tanhf(vg);
        hvB = sigm(vo) * tanhf(cstB);
      }
      st_h_llc(hout + sB * Hh + j0 + jB, f2bf(hvB));
    }
    // ---- flat barrier, epoch t+1 (+ xp[t+1] prefetch under barrier skew) ----
    asm volatile("s_waitcnt vmcnt(0)" ::: "memory");
    __syncthreads();
    if (tid == 0)
      __hip_atomic_store(flags + bid, t + 1, __ATOMIC_RELAXED, __HIP_MEMORY_SCOPE_AGENT);
    if (t + 1 < maxlen) {
      { const float* p = xp + (size_t)(sA * TMAX + t + 1) * G4 + j0 + jA;
        xiA = p[0]; xfA = p[Hh]; xgA = p[2 * Hh]; xoA = p[3 * Hh]; }
      if (tid < 128) {
        const float* q = xp + (size_t)(sB * TMAX + t + 1) * G4 + j0 + jB;
        xiB = q[0]; xfB = q[Hh]; xgB = q[2 * Hh]; xoB = q[3 * Hh];
      }
    }
    if (tid < NBLK) {
      unsigned spin = 0;
      while (__hip_atomic_load(flags + tid, __ATOMIC_RELAXED, __HIP_MEMORY_SCOPE_AGENT) < t + 1 &&
             ++spin < SPIN_CAP)
        __builtin_amdgcn_s_sleep(2);
    }
    __syncthreads();
  }

  // ---- fused output projection: block covers e-cols bid*4..+3 ----
  const unsigned short* hf = HBUF(maxlen);
  const int o = tid >> 2, p4 = tid & 3;     // 64 outputs/block, 4 K-parts each
  const int ee = o & 3, bb = o >> 2;
  const int e = bid * 4 + ee;
  const int hrow = (p4 < 2) ? bb : (16 + bb);
  const int kb = (p4 & 1) * 1152;
  const unsigned short* hp = hf + hrow * Hh + kb;
  const float* wp = wout + (size_t)e * 4608 + p4 * 1152;
  float acco = 0.f;
  #pragma unroll 4
  for (int i = 0; i < 1152; i += 8) {
    const u16x8 hv = *(const u16x8*)(hp + i);
    const float4 w0 = *(const float4*)(wp + i);
    const float4 w1 = *(const float4*)(wp + i + 4);
    acco += bf2f(hv[0]) * w0.x + bf2f(hv[1]) * w0.y + bf2f(hv[2]) * w0.z + bf2f(hv[3]) * w0.w
          + bf2f(hv[4]) * w1.x + bf2f(hv[5]) * w1.y + bf2f(hv[6]) * w1.z + bf2f(hv[7]) * w1.w;
  }
  acco += __shfl_xor(acco, 1);
  acco += __shfl_xor(acco, 2);
  if (p4 == 0) out[bb * 768 + e] = acco + bout[e];
}

extern "C" void kernel_launch(void* const* d_in, const int* in_sizes, int n_in,
                              void* d_out, int out_size, void* d_ws, size_t ws_size,
                              hipStream_t stream)
{
  const float* feat = (const float*)d_in[0];
  const int* mask   = (const int*)d_in[1];
  const int* start  = (const int*)d_in[2];
  const int* endp   = (const int*)d_in[3];
  const float* wih  = (const float*)d_in[4];
  const float* whh  = (const float*)d_in[5];
  const float* bih  = (const float*)d_in[6];
  const float* bhh  = (const float*)d_in[7];
  const float* wout = (const float*)d_in[8];
  const float* bout = (const float*)d_in[9];
  float* out = (float*)d_out;
  char* ws = (char*)d_ws;

  int* meta = (int*)ws;
  float* xp = (float*)(ws + XP_OFF);
  unsigned short* wihb = (unsigned short*)(ws + WIHB_OFF);
  unsigned short* abf  = (unsigned short*)(ws + ABF_OFF);
  unsigned short* hb   = (unsigned short*)(ws + HB_OFF);

  hipLaunchKernelGGL(prep_kernel, dim3(1), dim3(256), 0, stream, mask, start, endp, meta);
  hipLaunchKernelGGL(cast_wih_kernel, dim3(20736), dim3(256), 0, stream,
                     (const float4*)wih, (uint2*)wihb);
  hipLaunchKernelGGL(cast_a_kernel, dim3(1024), dim3(256), 0, stream,
                     feat, meta, (uint4*)abf);
  hipLaunchKernelGGL(xp_gemm, dim3(72, 8), dim3(256), 0, stream,
                     abf, wihb, bih, bhh, meta, xp);
  hipLaunchKernelGGL(lstm_persist, dim3(NBLK), dim3(256), 0, stream,
                     whh, xp, meta, hb, wout, bout, out);
}